// Round 1
// baseline (387.905 us; speedup 1.0000x reference)
//
#include <hip/hip_runtime.h>
#include <math.h>

// Problem constants
#define HID   4096
#define NH    32
#define D     128
#define I_    4096          // NH*D
#define QKV_ROWS 12288      // 3*I
#define TOTAL_ROWS 16448    // 12288 + 4096 + 32 + 32

// ws layout (floats)
#define WS_QKV   0
#define WS_Z     12288
#define WS_AB    16384      // a[32] then b[32]
#define WS_QN    16448
#define WS_KN    20544
#define WS_V     24640
#define WS_GB    28736      // g[32] then beta[32]
#define WS_VEC   28800

__device__ __forceinline__ float wave_reduce(float x) {
    for (int off = 32; off > 0; off >>= 1) x += __shfl_down(x, off, 64);
    return x;
}

// ---------------------------------------------------------------------------
// K1: all input matvecs. One 64-lane wave per row; 4 rows per 256-thread block.
// Rows: [0,12288) W_qkv -> qkv ; [12288,16384) W_z -> z ;
//       [16384,16416) W_a -> ab[0:32] ; [16416,16448) W_b -> ab[32:64]
// ---------------------------------------------------------------------------
__global__ __launch_bounds__(256) void matvec_all(
    const float* __restrict__ h,
    const float* __restrict__ Wqkv, const float* __restrict__ Wz,
    const float* __restrict__ Wa,   const float* __restrict__ Wb,
    float* __restrict__ ws)
{
    const int wave = threadIdx.x >> 6;
    const int lane = threadIdx.x & 63;
    const int row  = blockIdx.x * 4 + wave;

    const float* W; float* out; int r;
    if (row < QKV_ROWS)          { W = Wqkv; r = row;             out = ws + WS_QKV; }
    else if (row < 16384)        { W = Wz;   r = row - 12288;     out = ws + WS_Z;   }
    else if (row < 16416)        { W = Wa;   r = row - 16384;     out = ws + WS_AB;  }
    else                         { W = Wb;   r = row - 16416;     out = ws + WS_AB + 32; }

    const float4* wrow = (const float4*)(W + (size_t)r * HID);
    const float4* hv   = (const float4*)h;

    float acc = 0.f;
    #pragma unroll
    for (int i = 0; i < 16; ++i) {
        float4 wv = wrow[lane + i * 64];
        float4 hh = hv[lane + i * 64];
        acc = fmaf(wv.x, hh.x, acc);
        acc = fmaf(wv.y, hh.y, acc);
        acc = fmaf(wv.z, hh.z, acc);
        acc = fmaf(wv.w, hh.w, acc);
    }
    acc = wave_reduce(acc);
    if (lane == 0) out[r] = acc;
}

// ---------------------------------------------------------------------------
// K2: per-head conv + silu + l2norm(q,k) + g/beta.  32 blocks x 128 threads.
// Also writes new_conv_state (output region 2).
// ---------------------------------------------------------------------------
__global__ __launch_bounds__(128) void head_prep(
    const float* __restrict__ ws_in,       // qkv, ab
    const float* __restrict__ conv_state,  // (12288,3)
    const float* __restrict__ conv_w,      // (12288,4)
    const float* __restrict__ conv_b,      // (12288,)
    const float* __restrict__ A_log, const float* __restrict__ dt_bias,
    float* __restrict__ ncs_out,           // d_out + 528384, (12288,3)
    float* __restrict__ ws_out)            // qn,kn,v,g_beta
{
    const int hd = blockIdx.x;   // head
    const int e  = threadIdx.x;  // 0..127
    const float* qkv = ws_in + WS_QKV;

    float y[3];
    #pragma unroll
    for (int j = 0; j < 3; ++j) {
        const int c = j * I_ + hd * D + e;
        const float* cs = conv_state + (size_t)c * 3;
        const float* cw = conv_w     + (size_t)c * 4;
        const float x = qkv[c];
        float val = fmaf(cs[0], cw[0], fmaf(cs[1], cw[1],
                    fmaf(cs[2], cw[2], fmaf(x, cw[3], conv_b[c]))));
        y[j] = val / (1.f + expf(-val));  // silu
        // new_conv_state = shift-in
        ncs_out[(size_t)c * 3 + 0] = cs[1];
        ncs_out[(size_t)c * 3 + 1] = cs[2];
        ncs_out[(size_t)c * 3 + 2] = x;
    }

    // block-reduce sum of squares for q (y[0]) and k (y[1]) over 128 threads
    float sq = y[0] * y[0];
    float sk = y[1] * y[1];
    sq = wave_reduce(sq);
    sk = wave_reduce(sk);
    __shared__ float s_sq[2], s_sk[2];
    const int wave = threadIdx.x >> 6, lane = threadIdx.x & 63;
    if (lane == 0) { s_sq[wave] = sq; s_sk[wave] = sk; }
    __syncthreads();
    const float nq = sqrtf(s_sq[0] + s_sq[1]);
    const float nk = sqrtf(s_sk[0] + s_sk[1]);
    const float invq = (1.f / fmaxf(nq, 1e-6f)) * 0.08838834764831843f; // 1/sqrt(128)
    const float invk =  1.f / fmaxf(nk, 1e-6f);

    ws_out[WS_QN + hd * D + e] = y[0] * invq;
    ws_out[WS_KN + hd * D + e] = y[1] * invk;
    ws_out[WS_V  + hd * D + e] = y[2];

    if (threadIdx.x == 0) {
        const float a_ = ws_in[WS_AB + hd];
        const float b_ = ws_in[WS_AB + 32 + hd];
        const float x  = a_ + dt_bias[hd];
        const float sp = fmaxf(x, 0.f) + log1pf(expf(-fabsf(x)));  // softplus
        ws_out[WS_GB + hd]      = -expf(A_log[hd]) * sp;           // g
        ws_out[WS_GB + 32 + hd] = 1.f / (1.f + expf(-b_));         // beta
    }
}

// ---------------------------------------------------------------------------
// K3: per-head state update + RMSNorm + *silu(z). 32 blocks x 256 threads.
// Thread (half, e): half covers d in [half*64, half*64+64).
// core[e] = sum_d s[d,e]*qn[d] + delta[e]*sum_d kn[d]*qn[d]
// ---------------------------------------------------------------------------
__global__ __launch_bounds__(256) void state_update(
    const float* __restrict__ rnn_state,
    const float* __restrict__ ws,          // qn,kn,v,g_beta,z
    const float* __restrict__ norm_w,
    float* __restrict__ state_out,         // d_out + 4096
    float* __restrict__ vec_out)           // ws + WS_VEC
{
    const int hd   = blockIdx.x;
    const int tid  = threadIdx.x;
    const int e    = tid & 127;
    const int half = tid >> 7;           // 0 or 1
    const int d0   = half * 64;

    const float* S  = rnn_state + (size_t)hd * D * D;
    float*       So = state_out + (size_t)hd * D * D;
    const float eg   = expf(ws[WS_GB + hd]);
    const float beta = ws[WS_GB + 32 + hd];

    __shared__ float skn[128], sqn[128];
    if (half == 0) {
        skn[e] = ws[WS_KN + hd * D + e];
        sqn[e] = ws[WS_QN + hd * D + e];
    }
    __syncthreads();

    float kv = 0.f, cq = 0.f;
    #pragma unroll 4
    for (int d = d0; d < d0 + 64; ++d) {
        const float s = S[d * D + e] * eg;
        kv = fmaf(s, skn[d], kv);
        cq = fmaf(s, sqn[d], cq);
    }
    __shared__ float pkv[2][128], pcq[2][128];
    pkv[half][e] = kv; pcq[half][e] = cq;
    __syncthreads();
    const float kvt = pkv[0][e] + pkv[1][e];
    const float cqt = pcq[0][e] + pcq[1][e];

    float kq = 0.f;
    #pragma unroll 4
    for (int d = 0; d < 128; ++d) kq = fmaf(skn[d], sqn[d], kq);

    const float delta = (ws[WS_V + hd * D + e] - kvt) * beta;
    const float core  = cqt + delta * kq;

    #pragma unroll 4
    for (int d = d0; d < d0 + 64; ++d)
        So[d * D + e] = fmaf(skn[d], delta, S[d * D + e] * eg);

    // RMSNorm over e (128 values) using waves 0,1 (half==0)
    __shared__ float red[2];
    if (half == 0) {
        float c2 = wave_reduce(core * core);
        if ((tid & 63) == 0) red[tid >> 6] = c2;
    }
    __syncthreads();
    const float var = (red[0] + red[1]) * (1.f / 128.f);
    if (half == 0) {
        const float cn = norm_w[e] * core * rsqrtf(var + 1e-6f);
        const float zz = ws[WS_Z + hd * D + e];
        vec_out[hd * D + e] = cn * (zz / (1.f + expf(-zz)));
    }
}

// ---------------------------------------------------------------------------
// K4: out = W_out @ vec.  4096 rows, one wave per row.
// ---------------------------------------------------------------------------
__global__ __launch_bounds__(256) void matvec_out(
    const float* __restrict__ Wout, const float* __restrict__ vec,
    float* __restrict__ out)
{
    const int wave = threadIdx.x >> 6;
    const int lane = threadIdx.x & 63;
    const int row  = blockIdx.x * 4 + wave;

    const float4* wrow = (const float4*)(Wout + (size_t)row * I_);
    const float4* xv   = (const float4*)vec;

    float acc = 0.f;
    #pragma unroll
    for (int i = 0; i < 16; ++i) {
        float4 wv = wrow[lane + i * 64];
        float4 xx = xv[lane + i * 64];
        acc = fmaf(wv.x, xx.x, acc);
        acc = fmaf(wv.y, xx.y, acc);
        acc = fmaf(wv.z, xx.z, acc);
        acc = fmaf(wv.w, xx.w, acc);
    }
    acc = wave_reduce(acc);
    if (lane == 0) out[row] = acc;
}

// ---------------------------------------------------------------------------
extern "C" void kernel_launch(void* const* d_in, const int* in_sizes, int n_in,
                              void* d_out, int out_size, void* d_ws, size_t ws_size,
                              hipStream_t stream) {
    const float* hs         = (const float*)d_in[0];   // (4096,)
    const float* rnn_state  = (const float*)d_in[1];   // (32,128,128)
    const float* conv_state = (const float*)d_in[2];   // (12288,3)
    const float* W_qkv      = (const float*)d_in[3];   // (12288,4096)
    const float* W_z        = (const float*)d_in[4];   // (4096,4096)
    const float* W_a        = (const float*)d_in[5];   // (32,4096)
    const float* W_b        = (const float*)d_in[6];   // (32,4096)
    const float* conv_w     = (const float*)d_in[7];   // (12288,4)
    const float* conv_b     = (const float*)d_in[8];   // (12288,)
    const float* A_log      = (const float*)d_in[9];   // (32,)
    const float* dt_bias    = (const float*)d_in[10];  // (32,)
    const float* norm_w     = (const float*)d_in[11];  // (128,)
    const float* W_out      = (const float*)d_in[12];  // (4096,4096)

    float* out       = (float*)d_out;                  // [0, 4096)
    float* state_out = (float*)d_out + 4096;           // [4096, 528384)
    float* ncs_out   = (float*)d_out + 4096 + NH * D * D; // [528384, 565248)
    float* ws        = (float*)d_ws;

    matvec_all<<<TOTAL_ROWS / 4, 256, 0, stream>>>(hs, W_qkv, W_z, W_a, W_b, ws);
    head_prep<<<NH, 128, 0, stream>>>(ws, conv_state, conv_w, conv_b,
                                      A_log, dt_bias, ncs_out, ws);
    state_update<<<NH, 256, 0, stream>>>(rnn_state, ws, norm_w, state_out,
                                         ws + WS_VEC);
    matvec_out<<<I_ / 4, 256, 0, stream>>>(W_out, ws + WS_VEC, out);
}

// Round 2
// 375.933 us; speedup vs baseline: 1.0318x; 1.0318x over previous
//
#include <hip/hip_runtime.h>
#include <math.h>

// Problem constants
#define HID   4096
#define NH    32
#define D     128
#define I_    4096          // NH*D
#define QKV_ROWS 12288      // 3*I
#define TOTAL_ROWS 16448    // 12288 + 4096 + 32 + 32

// ws layout (floats)
#define WS_QKV   0
#define WS_Z     12288
#define WS_AB    16384      // a[32] then b[32]
#define WS_VEC   16448      // core_normed * silu(z), 4096 floats

__device__ __forceinline__ float wave_reduce(float x) {
    for (int off = 32; off > 0; off >>= 1) x += __shfl_down(x, off, 64);
    return x;
}

// ---------------------------------------------------------------------------
// K1: all input matvecs. One 64-lane wave per row; 4 rows per 256-thread block.
// Rows: [0,12288) W_qkv -> qkv ; [12288,16384) W_z -> z ;
//       [16384,16416) W_a -> ab[0:32] ; [16416,16448) W_b -> ab[32:64]
// Memory-bound: 263 MB of weights. h (16 KB) stays L1-hot.
// ---------------------------------------------------------------------------
__global__ __launch_bounds__(256) void matvec_all(
    const float* __restrict__ h,
    const float* __restrict__ Wqkv, const float* __restrict__ Wz,
    const float* __restrict__ Wa,   const float* __restrict__ Wb,
    float* __restrict__ ws)
{
    const int wave = threadIdx.x >> 6;
    const int lane = threadIdx.x & 63;
    const int row  = blockIdx.x * 4 + wave;

    const float* W; float* out; int r;
    if (row < QKV_ROWS)          { W = Wqkv; r = row;             out = ws + WS_QKV; }
    else if (row < 16384)        { W = Wz;   r = row - 12288;     out = ws + WS_Z;   }
    else if (row < 16416)        { W = Wa;   r = row - 16384;     out = ws + WS_AB;  }
    else                         { W = Wb;   r = row - 16416;     out = ws + WS_AB + 32; }

    const float4* wrow = (const float4*)(W + (size_t)r * HID);
    const float4* hv   = (const float4*)h;

    float acc = 0.f;
    #pragma unroll
    for (int i = 0; i < 16; ++i) {
        float4 wv = wrow[lane + i * 64];
        float4 hh = hv[lane + i * 64];
        acc = fmaf(wv.x, hh.x, acc);
        acc = fmaf(wv.y, hh.y, acc);
        acc = fmaf(wv.z, hh.z, acc);
        acc = fmaf(wv.w, hh.w, acc);
    }
    acc = wave_reduce(acc);
    if (lane == 0) out[r] = acc;
}

// ---------------------------------------------------------------------------
// K2: fused per-head pipeline. 32 blocks x 1024 threads (16 waves).
// Phase A: conv+silu for this head's q,k,v channels (384 threads), ncs write,
//          g/beta (thread 0).
// Phase B: l2norms of q,k (2 waves), normalized kn/qn into LDS.
// Phase C: state read ONCE into regs (x16/thread, pre-scaled by e^g),
//          kv_mem / core-q partial reductions, kq partials.
// Phase D: combine -> delta, core; RMS reduce.
// Phase E: state store from regs; vec = norm_w*core*rsqrt(var)*silu(z).
// Thread map for state: e = tid & 127 (column), dgrp = tid >> 7 (d-slice of 16).
// ---------------------------------------------------------------------------
__global__ __launch_bounds__(1024) void head_fused(
    const float* __restrict__ ws_in,       // qkv, z, ab
    const float* __restrict__ rnn_state,   // (32,128,128)
    const float* __restrict__ conv_state,  // (12288,3)
    const float* __restrict__ conv_w,      // (12288,4)
    const float* __restrict__ conv_b,      // (12288,)
    const float* __restrict__ A_log, const float* __restrict__ dt_bias,
    const float* __restrict__ norm_w,
    float* __restrict__ state_out,         // d_out + 4096
    float* __restrict__ ncs_out,           // d_out + 528384, (12288,3)
    float* __restrict__ vec_out)           // ws + WS_VEC
{
    const int hd   = blockIdx.x;
    const int tid  = threadIdx.x;
    const int e    = tid & 127;
    const int dgrp = tid >> 7;            // 0..7
    const int d0   = dgrp * 16;

    __shared__ float sy[3][D];            // silu(conv) for q,k,v
    __shared__ float skn[D], sqn[D];      // normalized k, q (indexed by d)
    __shared__ float pkv[8][D], pcq[8][D];
    __shared__ float pkq[8];
    __shared__ float sgb[2];              // g, beta
    __shared__ float snrm[2];             // sumsq q, k
    __shared__ float sdelta[D], score[D];
    __shared__ float red[2];

    // ---- Phase A: conv + silu + new_conv_state ----
    if (tid < 384) {
        const int j  = tid >> 7;          // 0=q 1=k 2=v
        const int e2 = tid & 127;
        const int c  = j * I_ + hd * D + e2;
        const float* cs = conv_state + (size_t)c * 3;
        const float* cw = conv_w     + (size_t)c * 4;
        const float x = ws_in[WS_QKV + c];
        float val = fmaf(cs[0], cw[0], fmaf(cs[1], cw[1],
                    fmaf(cs[2], cw[2], fmaf(x, cw[3], conv_b[c]))));
        sy[j][e2] = val / (1.f + expf(-val));  // silu
        ncs_out[(size_t)c * 3 + 0] = cs[1];
        ncs_out[(size_t)c * 3 + 1] = cs[2];
        ncs_out[(size_t)c * 3 + 2] = x;
    }
    if (tid == 0) {
        const float a_ = ws_in[WS_AB + hd];
        const float b_ = ws_in[WS_AB + 32 + hd];
        const float x  = a_ + dt_bias[hd];
        const float sp = fmaxf(x, 0.f) + log1pf(expf(-fabsf(x)));  // softplus
        sgb[0] = -expf(A_log[hd]) * sp;                            // g
        sgb[1] = 1.f / (1.f + expf(-b_));                          // beta
    }
    __syncthreads();

    // ---- Phase B: l2 norms of q (wave 0) and k (wave 1) ----
    if (tid < 128) {
        const int w = tid >> 6, lane = tid & 63;
        const float v0 = sy[w][lane], v1 = sy[w][lane + 64];
        const float ss = wave_reduce(fmaf(v0, v0, v1 * v1));
        if (lane == 0) snrm[w] = ss;
    }
    __syncthreads();
    const float invq = (1.f / fmaxf(sqrtf(snrm[0]), 1e-6f)) * 0.08838834764831843f; // *1/sqrt(128)
    const float invk =  1.f / fmaxf(sqrtf(snrm[1]), 1e-6f);
    if (tid < 128) {
        sqn[tid] = sy[0][tid] * invq;
        skn[tid] = sy[1][tid] * invk;
    }
    __syncthreads();

    // ---- Phase C: state read (once) + partial reductions ----
    const float eg   = expf(sgb[0]);
    const float beta = sgb[1];
    const float* Sp = rnn_state + (size_t)hd * D * D + (size_t)d0 * D + e;

    float sreg[16];
    #pragma unroll
    for (int j = 0; j < 16; ++j) sreg[j] = Sp[j * D] * eg;

    float kv = 0.f, cq = 0.f;
    #pragma unroll
    for (int j = 0; j < 16; ++j) {
        kv = fmaf(sreg[j], skn[d0 + j], kv);
        cq = fmaf(sreg[j], sqn[d0 + j], cq);
    }
    pkv[dgrp][e] = kv;
    pcq[dgrp][e] = cq;
    if (e == 0) {
        float t = 0.f;
        #pragma unroll
        for (int j = 0; j < 16; ++j) t = fmaf(skn[d0 + j], sqn[d0 + j], t);
        pkq[dgrp] = t;
    }
    __syncthreads();

    // ---- Phase D: combine, delta, core, RMS reduce ----
    if (tid < 128) {
        float kvt = 0.f, cqt = 0.f, kq = 0.f;
        #pragma unroll
        for (int g = 0; g < 8; ++g) {
            kvt += pkv[g][tid];
            cqt += pcq[g][tid];
            kq  += pkq[g];
        }
        const float delta = (sy[2][tid] - kvt) * beta;
        sdelta[tid] = delta;
        const float core = fmaf(delta, kq, cqt);
        score[tid] = core;
        const float c2 = wave_reduce(core * core);
        if ((tid & 63) == 0) red[tid >> 6] = c2;
    }
    __syncthreads();

    // ---- Phase E: state store from registers + output vector ----
    float* So = state_out + (size_t)hd * D * D + (size_t)d0 * D + e;
    const float de = sdelta[e];
    #pragma unroll
    for (int j = 0; j < 16; ++j)
        So[j * D] = fmaf(skn[d0 + j], de, sreg[j]);

    if (tid < 128) {
        const float var = (red[0] + red[1]) * (1.f / 128.f);
        const float cn  = norm_w[tid] * score[tid] * rsqrtf(var + 1e-6f);
        const float zz  = ws_in[WS_Z + hd * D + tid];
        vec_out[hd * D + tid] = cn * (zz / (1.f + expf(-zz)));
    }
}

// ---------------------------------------------------------------------------
// K3: out = W_out @ vec.  4096 rows, one wave per row.
// ---------------------------------------------------------------------------
__global__ __launch_bounds__(256) void matvec_out(
    const float* __restrict__ Wout, const float* __restrict__ vec,
    float* __restrict__ out)
{
    const int wave = threadIdx.x >> 6;
    const int lane = threadIdx.x & 63;
    const int row  = blockIdx.x * 4 + wave;

    const float4* wrow = (const float4*)(Wout + (size_t)row * I_);
    const float4* xv   = (const float4*)vec;

    float acc = 0.f;
    #pragma unroll
    for (int i = 0; i < 16; ++i) {
        float4 wv = wrow[lane + i * 64];
        float4 xx = xv[lane + i * 64];
        acc = fmaf(wv.x, xx.x, acc);
        acc = fmaf(wv.y, xx.y, acc);
        acc = fmaf(wv.z, xx.z, acc);
        acc = fmaf(wv.w, xx.w, acc);
    }
    acc = wave_reduce(acc);
    if (lane == 0) out[row] = acc;
}

// ---------------------------------------------------------------------------
extern "C" void kernel_launch(void* const* d_in, const int* in_sizes, int n_in,
                              void* d_out, int out_size, void* d_ws, size_t ws_size,
                              hipStream_t stream) {
    const float* hs         = (const float*)d_in[0];   // (4096,)
    const float* rnn_state  = (const float*)d_in[1];   // (32,128,128)
    const float* conv_state = (const float*)d_in[2];   // (12288,3)
    const float* W_qkv      = (const float*)d_in[3];   // (12288,4096)
    const float* W_z        = (const float*)d_in[4];   // (4096,4096)
    const float* W_a        = (const float*)d_in[5];   // (32,4096)
    const float* W_b        = (const float*)d_in[6];   // (32,4096)
    const float* conv_w     = (const float*)d_in[7];   // (12288,4)
    const float* conv_b     = (const float*)d_in[8];   // (12288,)
    const float* A_log      = (const float*)d_in[9];   // (32,)
    const float* dt_bias    = (const float*)d_in[10];  // (32,)
    const float* norm_w     = (const float*)d_in[11];  // (128,)
    const float* W_out      = (const float*)d_in[12];  // (4096,4096)

    float* out       = (float*)d_out;                     // [0, 4096)
    float* state_out = (float*)d_out + 4096;              // [4096, 528384)
    float* ncs_out   = (float*)d_out + 4096 + NH * D * D; // [528384, 565248)
    float* ws        = (float*)d_ws;

    matvec_all<<<TOTAL_ROWS / 4, 256, 0, stream>>>(hs, W_qkv, W_z, W_a, W_b, ws);
    head_fused<<<NH, 1024, 0, stream>>>(ws, rnn_state, conv_state, conv_w, conv_b,
                                        A_log, dt_bias, norm_w,
                                        state_out, ncs_out, ws + WS_VEC);
    matvec_out<<<I_ / 4, 256, 0, stream>>>(W_out, ws + WS_VEC, out);
}

// Round 3
// 358.679 us; speedup vs baseline: 1.0815x; 1.0481x over previous
//
#include <hip/hip_runtime.h>
#include <math.h>

// Problem constants
#define HID   4096
#define NH    32
#define D     128
#define I_    4096          // NH*D
#define QKV_ROWS 12288      // 3*I
#define TOTAL_ROWS 16448    // 12288 + 4096 + 32 + 32

// ws layout (floats)
#define WS_QKV   0
#define WS_Z     12288
#define WS_AB    16384      // a[32] then b[32]
#define WS_VEC   16448      // core_normed * silu(z), 4096 floats

typedef float f4 __attribute__((ext_vector_type(4)));

__device__ __forceinline__ float wave_reduce(float x) {
    for (int off = 32; off > 0; off >>= 1) x += __shfl_down(x, off, 64);
    return x;
}

// ---------------------------------------------------------------------------
// K1: all input matvecs. One 64-lane wave per row; 4 rows per 256-thread block.
// Weights are streamed exactly once -> nontemporal loads (keep L2 for h).
// ---------------------------------------------------------------------------
__global__ __launch_bounds__(256) void matvec_all(
    const float* __restrict__ h,
    const float* __restrict__ Wqkv, const float* __restrict__ Wz,
    const float* __restrict__ Wa,   const float* __restrict__ Wb,
    float* __restrict__ ws)
{
    const int wave = threadIdx.x >> 6;
    const int lane = threadIdx.x & 63;
    const int row  = blockIdx.x * 4 + wave;

    const float* W; float* out; int r;
    if (row < QKV_ROWS)          { W = Wqkv; r = row;             out = ws + WS_QKV; }
    else if (row < 16384)        { W = Wz;   r = row - 12288;     out = ws + WS_Z;   }
    else if (row < 16416)        { W = Wa;   r = row - 16384;     out = ws + WS_AB;  }
    else                         { W = Wb;   r = row - 16416;     out = ws + WS_AB + 32; }

    const f4* wrow = (const f4*)(W + (size_t)r * HID);
    const f4* hv   = (const f4*)h;

    float acc = 0.f;
    #pragma unroll
    for (int i = 0; i < 16; ++i) {
        const f4 wv = __builtin_nontemporal_load(wrow + lane + i * 64);
        const f4 hh = hv[lane + i * 64];
        acc = fmaf(wv.x, hh.x, acc);
        acc = fmaf(wv.y, hh.y, acc);
        acc = fmaf(wv.z, hh.z, acc);
        acc = fmaf(wv.w, hh.w, acc);
    }
    acc = wave_reduce(acc);
    if (lane == 0) out[r] = acc;
}

// ---------------------------------------------------------------------------
// K2: fused per-head pipeline. 32 blocks x 1024 threads (16 waves).
// Phases: A conv+silu+ncs+g/beta, B l2norms, C state->regs + partials,
//         D delta/core/RMS, E state store + vec.
// ---------------------------------------------------------------------------
__global__ __launch_bounds__(1024) void head_fused(
    const float* __restrict__ ws_in,       // qkv, z, ab
    const float* __restrict__ rnn_state,   // (32,128,128)
    const float* __restrict__ conv_state,  // (12288,3)
    const float* __restrict__ conv_w,      // (12288,4)
    const float* __restrict__ conv_b,      // (12288,)
    const float* __restrict__ A_log, const float* __restrict__ dt_bias,
    const float* __restrict__ norm_w,
    float* __restrict__ state_out,         // d_out + 4096
    float* __restrict__ ncs_out,           // d_out + 528384, (12288,3)
    float* __restrict__ vec_out)           // ws + WS_VEC
{
    const int hd   = blockIdx.x;
    const int tid  = threadIdx.x;
    const int e    = tid & 127;
    const int dgrp = tid >> 7;            // 0..7
    const int d0   = dgrp * 16;

    __shared__ float sy[3][D];            // silu(conv) for q,k,v
    __shared__ float skn[D], sqn[D];      // normalized k, q (indexed by d)
    __shared__ float pkv[8][D], pcq[8][D];
    __shared__ float pkq[8];
    __shared__ float sgb[2];              // g, beta
    __shared__ float snrm[2];             // sumsq q, k
    __shared__ float sdelta[D], score[D];
    __shared__ float red[2];

    // ---- Phase A: conv + silu + new_conv_state ----
    if (tid < 384) {
        const int j  = tid >> 7;          // 0=q 1=k 2=v
        const int e2 = tid & 127;
        const int c  = j * I_ + hd * D + e2;
        const float* cs = conv_state + (size_t)c * 3;
        const f4 cw = *(const f4*)(conv_w + (size_t)c * 4);
        const float cs0 = cs[0], cs1 = cs[1], cs2 = cs[2];
        const float x = ws_in[WS_QKV + c];
        float val = fmaf(cs0, cw.x, fmaf(cs1, cw.y,
                    fmaf(cs2, cw.z, fmaf(x, cw.w, conv_b[c]))));
        sy[j][e2] = val / (1.f + expf(-val));  // silu
        ncs_out[(size_t)c * 3 + 0] = cs1;
        ncs_out[(size_t)c * 3 + 1] = cs2;
        ncs_out[(size_t)c * 3 + 2] = x;
    }
    if (tid == 0) {
        const float a_ = ws_in[WS_AB + hd];
        const float b_ = ws_in[WS_AB + 32 + hd];
        const float x  = a_ + dt_bias[hd];
        const float sp = fmaxf(x, 0.f) + log1pf(expf(-fabsf(x)));  // softplus
        sgb[0] = -expf(A_log[hd]) * sp;                            // g
        sgb[1] = 1.f / (1.f + expf(-b_));                          // beta
    }
    __syncthreads();

    // ---- Phase B: l2 norms of q (wave 0) and k (wave 1) ----
    if (tid < 128) {
        const int w = tid >> 6, lane = tid & 63;
        const float v0 = sy[w][lane], v1 = sy[w][lane + 64];
        const float ss = wave_reduce(fmaf(v0, v0, v1 * v1));
        if (lane == 0) snrm[w] = ss;
    }
    __syncthreads();
    const float invq = (1.f / fmaxf(sqrtf(snrm[0]), 1e-6f)) * 0.08838834764831843f; // *1/sqrt(128)
    const float invk =  1.f / fmaxf(sqrtf(snrm[1]), 1e-6f);
    if (tid < 128) {
        sqn[tid] = sy[0][tid] * invq;
        skn[tid] = sy[1][tid] * invk;
    }
    __syncthreads();

    // ---- Phase C: state read (once) + partial reductions ----
    const float eg   = expf(sgb[0]);
    const float beta = sgb[1];
    const float* Sp = rnn_state + (size_t)hd * D * D + (size_t)d0 * D + e;

    float sreg[16];
    #pragma unroll
    for (int j = 0; j < 16; ++j) sreg[j] = Sp[j * D] * eg;

    float kv = 0.f, cq = 0.f;
    #pragma unroll
    for (int j = 0; j < 16; ++j) {
        kv = fmaf(sreg[j], skn[d0 + j], kv);
        cq = fmaf(sreg[j], sqn[d0 + j], cq);
    }
    pkv[dgrp][e] = kv;
    pcq[dgrp][e] = cq;
    if (e == 0) {
        float t = 0.f;
        #pragma unroll
        for (int j = 0; j < 16; ++j) t = fmaf(skn[d0 + j], sqn[d0 + j], t);
        pkq[dgrp] = t;
    }
    __syncthreads();

    // ---- Phase D: combine, delta, core, RMS reduce ----
    if (tid < 128) {
        float kvt = 0.f, cqt = 0.f, kq = 0.f;
        #pragma unroll
        for (int g = 0; g < 8; ++g) {
            kvt += pkv[g][tid];
            cqt += pcq[g][tid];
            kq  += pkq[g];
        }
        const float delta = (sy[2][tid] - kvt) * beta;
        sdelta[tid] = delta;
        const float core = fmaf(delta, kq, cqt);
        score[tid] = core;
        const float c2 = wave_reduce(core * core);
        if ((tid & 63) == 0) red[tid >> 6] = c2;
    }
    __syncthreads();

    // ---- Phase E: state store from registers + output vector ----
    float* So = state_out + (size_t)hd * D * D + (size_t)d0 * D + e;
    const float de = sdelta[e];
    #pragma unroll
    for (int j = 0; j < 16; ++j)
        So[j * D] = fmaf(skn[d0 + j], de, sreg[j]);

    if (tid < 128) {
        const float var = (red[0] + red[1]) * (1.f / 128.f);
        const float cn  = norm_w[tid] * score[tid] * rsqrtf(var + 1e-6f);
        const float zz  = ws_in[WS_Z + hd * D + tid];
        vec_out[hd * D + tid] = cn * (zz / (1.f + expf(-zz)));
    }
}

// ---------------------------------------------------------------------------
// K3: out = W_out @ vec.  4096 rows, one wave per row. Nontemporal weights.
// ---------------------------------------------------------------------------
__global__ __launch_bounds__(256) void matvec_out(
    const float* __restrict__ Wout, const float* __restrict__ vec,
    float* __restrict__ out)
{
    const int wave = threadIdx.x >> 6;
    const int lane = threadIdx.x & 63;
    const int row  = blockIdx.x * 4 + wave;

    const f4* wrow = (const f4*)(Wout + (size_t)row * I_);
    const f4* xv   = (const f4*)vec;

    float acc = 0.f;
    #pragma unroll
    for (int i = 0; i < 16; ++i) {
        const f4 wv = __builtin_nontemporal_load(wrow + lane + i * 64);
        const f4 xx = xv[lane + i * 64];
        acc = fmaf(wv.x, xx.x, acc);
        acc = fmaf(wv.y, xx.y, acc);
        acc = fmaf(wv.z, xx.z, acc);
        acc = fmaf(wv.w, xx.w, acc);
    }
    acc = wave_reduce(acc);
    if (lane == 0) out[row] = acc;
}

// ---------------------------------------------------------------------------
extern "C" void kernel_launch(void* const* d_in, const int* in_sizes, int n_in,
                              void* d_out, int out_size, void* d_ws, size_t ws_size,
                              hipStream_t stream) {
    const float* hs         = (const float*)d_in[0];   // (4096,)
    const float* rnn_state  = (const float*)d_in[1];   // (32,128,128)
    const float* conv_state = (const float*)d_in[2];   // (12288,3)
    const float* W_qkv      = (const float*)d_in[3];   // (12288,4096)
    const float* W_z        = (const float*)d_in[4];   // (4096,4096)
    const float* W_a        = (const float*)d_in[5];   // (32,4096)
    const float* W_b        = (const float*)d_in[6];   // (32,4096)
    const float* conv_w     = (const float*)d_in[7];   // (12288,4)
    const float* conv_b     = (const float*)d_in[8];   // (12288,)
    const float* A_log      = (const float*)d_in[9];   // (32,)
    const float* dt_bias    = (const float*)d_in[10];  // (32,)
    const float* norm_w     = (const float*)d_in[11];  // (128,)
    const float* W_out      = (const float*)d_in[12];  // (4096,4096)

    float* out       = (float*)d_out;                     // [0, 4096)
    float* state_out = (float*)d_out + 4096;              // [4096, 528384)
    float* ncs_out   = (float*)d_out + 4096 + NH * D * D; // [528384, 565248)
    float* ws        = (float*)d_ws;

    matvec_all<<<TOTAL_ROWS / 4, 256, 0, stream>>>(hs, W_qkv, W_z, W_a, W_b, ws);
    head_fused<<<NH, 1024, 0, stream>>>(ws, rnn_state, conv_state, conv_w, conv_b,
                                        A_log, dt_bias, norm_w,
                                        state_out, ncs_out, ws + WS_VEC);
    matvec_out<<<I_ / 4, 256, 0, stream>>>(W_out, ws + WS_VEC, out);
}